// Round 5
// baseline (181.286 us; speedup 1.0000x reference)
//
#include <hip/hip_runtime.h>
#include <hip/hip_bf16.h>

#define Bv 32
#define Dv 512
#define Kv 64
#define Nv 1024
#define EPSv 1e-12f

typedef __attribute__((ext_vector_type(8))) short bf16x8;
typedef __attribute__((ext_vector_type(4))) float f32x4;

// fp32 -> bf16 (RNE), bit-level
__device__ __forceinline__ unsigned short f2b(float f) {
  union { float f; unsigned u; } v; v.f = f;
  unsigned r = v.u + 0x7fffu + ((v.u >> 16) & 1u);
  return (unsigned short)(r >> 16);
}
__device__ __forceinline__ unsigned pack2(float a, float b) {
  return (unsigned)f2b(a) | ((unsigned)f2b(b) << 16);
}

// ---------------------------------------------------------------------------
// Kernel W: convert conv_w (K x D fp32) -> bf16. 32 blocks x 256 thr.
// ---------------------------------------------------------------------------
__global__ __launch_bounds__(256) void wconv(const float* __restrict__ w,
                                             unsigned short* __restrict__ wbf) {
  int i = (blockIdx.x * 256 + threadIdx.x) * 4;
  float4 v = *(const float4*)&w[i];
  uint2 o = make_uint2(pack2(v.x, v.y), pack2(v.z, v.w));
  *(uint2*)&wbf[i] = o;
}

// ---------------------------------------------------------------------------
// Kernel F (R10): FULLY FUSED scores+softmax+vlad. No xbf, no assign
// round-trip (the ~25us materialization tax measured across R5..R9).
// Block (b, dq): owns vlad d-range [dq*128, +128), loops all 16 n-chunks:
//   stage x[b][:][chunk] -> LDS xT[n][d] (scores operand, rotation-swizzled)
//                        -> LDS x_dn[dd][n] (PV operand, block's 128-d only)
//   scores 64k x 64n MFMA (dup x4 across dq; +6.4 GF total, cheap)
//   softmax over k (same shuffle+LDS scheme as before)
//   P -> LDS p_kn bf16; asum accumulated in registers (block-local!)
//   PV: accv[kt] += mfma(x_dn frag, p_kn frag)  (16 acc VGPR/thread)
// Epilogue: val = accv - centers*asum; write vlad; colsq via global atomics.
// T14 async-stage: chunk c+1's 16 global loads issue during PV phase, held
// in 64 VGPRs; consumption separated by 2 __syncthreads -> cannot be sunk.
// XCD-swizzle: 4 dq-siblings of same b land on same XCD -> x[b] L2-shared.
// LDS: 66560(xT)+18432(x_dn)+9216(p_kn)+2048(red)+512(asum) = 96.7 KB.
// Grid 128 blocks x 512 thr.
// ---------------------------------------------------------------------------
__global__ __launch_bounds__(512, 2) void fused_all(
    const float* __restrict__ x, const unsigned short* __restrict__ wbf,
    const float* __restrict__ centers,
    float* __restrict__ vlad, float* __restrict__ colsq) {
  __shared__ unsigned short xT[64 * 520];    // [n][d] pitch 520
  __shared__ unsigned short x_dn[128 * 72];  // [dd][n] pitch 72
  __shared__ unsigned short p_kn[64 * 72];   // [k][n] pitch 72
  __shared__ float redmax[4][64];
  __shared__ float redsum[4][64];
  __shared__ float asum_sh[2][64];

  const int t = threadIdx.x;
  // XCD-aware decode: blocks flat%8 land on XCD flat%8 (round-robin).
  // Give each XCD 4 consecutive b values, 4 dq each.
  const int flat = blockIdx.x;            // 0..127
  const int c8 = flat & 7;
  const int j = flat >> 3;                // 0..15
  const int b = c8 * 4 + (j >> 2);        // 0..31
  const int dq = j & 3;                   // 0..3
  const int dbase = dq * 128;

  const int lo = t & 15;                  // n-quad
  const int hi = t >> 4;                  // 0..31
  const int s = (lo >> 1) & 3;            // xT write-rotation (bank spread)
  const float* xb = x + (size_t)b * Dv * Nv;

  const int wv = t >> 6, lane = t & 63, q = lane >> 4, m = lane & 15;
  const int k16 = wv & 3, nsub = wv >> 2;

  const unsigned short* wp = wbf + (size_t)(k16 * 16 + m) * Dv + q * 8;
  const unsigned short* l0 = &xT[(nsub * 32 + m) * 520 + q * 8];
  const unsigned short* l1 = l0 + 16 * 520;

  f32x4 accv0 = {0.f,0.f,0.f,0.f}, accv1 = {0.f,0.f,0.f,0.f};
  f32x4 accv2 = {0.f,0.f,0.f,0.f}, accv3 = {0.f,0.f,0.f,0.f};
  float asum_acc[4] = {0.f, 0.f, 0.f, 0.f};

  // prefetch chunk 0 into registers
  float4 xp0[8], xp1[8];
#pragma unroll
  for (int r = 0; r < 8; r++) {
    const float* src = &xb[(size_t)((hi + 32 * r) * 2) * Nv + lo * 4];
    xp0[r] = *(const float4*)src;
    xp1[r] = *(const float4*)(src + Nv);
  }

  for (int c = 0; c < 16; ++c) {
    // ---- stage regs -> LDS (xT rotated; x_dn for this block's d-window) ----
#pragma unroll
    for (int r = 0; r < 8; r++) {
      int d = (hi + 32 * r) * 2;
      int n4 = lo * 4;
      float4 v0 = xp0[r], v1 = xp1[r];
      unsigned w0 = pack2(v0.x, v1.x);
      unsigned w1 = pack2(v0.y, v1.y);
      unsigned w2 = pack2(v0.z, v1.z);
      unsigned w3 = pack2(v0.w, v1.w);
      unsigned a0 = (s & 1) ? w1 : w0, a1 = (s & 1) ? w2 : w1,
               a2 = (s & 1) ? w3 : w2, a3 = (s & 1) ? w0 : w3;
      unsigned b0 = (s & 2) ? a2 : a0, b1 = (s & 2) ? a3 : a1,
               b2 = (s & 2) ? a0 : a2, b3 = (s & 2) ? a1 : a3;
      *(unsigned*)&xT[(n4 + ((0 + s) & 3)) * 520 + d] = b0;
      *(unsigned*)&xT[(n4 + ((1 + s) & 3)) * 520 + d] = b1;
      *(unsigned*)&xT[(n4 + ((2 + s) & 3)) * 520 + d] = b2;
      *(unsigned*)&xT[(n4 + ((3 + s) & 3)) * 520 + d] = b3;
      if ((r >> 1) == dq) {
        int dd = d - dbase;
        *(uint2*)&x_dn[dd * 72 + n4] =
            make_uint2(pack2(v0.x, v0.y), pack2(v0.z, v0.w));
        *(uint2*)&x_dn[(dd + 1) * 72 + n4] =
            make_uint2(pack2(v1.x, v1.y), pack2(v1.z, v1.w));
      }
    }
    __syncthreads();   // bar_A: tiles visible

    // ---- scores GEMM (64k x 64n, contraction d=512) ----
    f32x4 acc0 = {0.f,0.f,0.f,0.f};
    f32x4 acc1 = {0.f,0.f,0.f,0.f};
#pragma unroll
    for (int d0 = 0; d0 < Dv; d0 += 32) {
      bf16x8 af = *(const bf16x8*)(wp + d0);
      bf16x8 bf0 = *(const bf16x8*)(l0 + d0);
      bf16x8 bf1 = *(const bf16x8*)(l1 + d0);
      acc0 = __builtin_amdgcn_mfma_f32_16x16x32_bf16(af, bf0, acc0, 0, 0, 0);
      acc1 = __builtin_amdgcn_mfma_f32_16x16x32_bf16(af, bf1, acc1, 0, 0, 0);
    }

    // ---- softmax over k (64) ----
    float m0 = fmaxf(fmaxf(acc0[0], acc0[1]), fmaxf(acc0[2], acc0[3]));
    float m1 = fmaxf(fmaxf(acc1[0], acc1[1]), fmaxf(acc1[2], acc1[3]));
    m0 = fmaxf(m0, __shfl_xor(m0, 16)); m0 = fmaxf(m0, __shfl_xor(m0, 32));
    m1 = fmaxf(m1, __shfl_xor(m1, 16)); m1 = fmaxf(m1, __shfl_xor(m1, 32));
    if (q == 0) {
      redmax[k16][nsub * 32 + m] = m0;
      redmax[k16][nsub * 32 + 16 + m] = m1;
    }
    __syncthreads();   // bar_B
    const int c0i = nsub * 32 + m, c1i = c0i + 16;
    float mc0 = fmaxf(fmaxf(redmax[0][c0i], redmax[1][c0i]),
                      fmaxf(redmax[2][c0i], redmax[3][c0i]));
    float mc1 = fmaxf(fmaxf(redmax[0][c1i], redmax[1][c1i]),
                      fmaxf(redmax[2][c1i], redmax[3][c1i]));

    float e0[4], e1[4];
    float s0 = 0.f, s1 = 0.f;
#pragma unroll
    for (int r = 0; r < 4; r++) {
      e0[r] = __expf(acc0[r] - mc0); s0 += e0[r];
      e1[r] = __expf(acc1[r] - mc1); s1 += e1[r];
    }
    s0 += __shfl_xor(s0, 16); s0 += __shfl_xor(s0, 32);
    s1 += __shfl_xor(s1, 16); s1 += __shfl_xor(s1, 32);
    if (q == 0) {
      redsum[k16][c0i] = s0;
      redsum[k16][c1i] = s1;
    }
    __syncthreads();   // bar_C
    float sc0 = 1.0f / (redsum[0][c0i] + redsum[1][c0i] + redsum[2][c0i] + redsum[3][c0i]);
    float sc1 = 1.0f / (redsum[0][c1i] + redsum[1][c1i] + redsum[2][c1i] + redsum[3][c1i]);

    // ---- P -> LDS (bf16) + asum register accumulation ----
#pragma unroll
    for (int r = 0; r < 4; r++) {
      float v0 = e0[r] * sc0;
      float v1 = e1[r] * sc1;
      int krow = k16 * 16 + q * 4 + r;
      p_kn[krow * 72 + nsub * 32 + m] = f2b(v0);
      p_kn[krow * 72 + nsub * 32 + 16 + m] = f2b(v1);
      float p = v0 + v1;
      p += __shfl_xor(p, 1); p += __shfl_xor(p, 2);
      p += __shfl_xor(p, 4); p += __shfl_xor(p, 8);
      asum_acc[r] += p;
    }
    __syncthreads();   // bar_D: p_kn visible

    // ---- T14: issue next chunk's x loads during PV phase ----
    if (c < 15) {
      const float* xcn = xb + (size_t)(c + 1) * 64;
#pragma unroll
      for (int r = 0; r < 8; r++) {
        const float* src = &xcn[(size_t)((hi + 32 * r) * 2) * Nv + lo * 4];
        xp0[r] = *(const float4*)src;
        xp1[r] = *(const float4*)(src + Nv);
      }
    }

    // ---- PV: accv[kt] += x_dn(frag, rows wv*16+m) * p_kn(frag, rows kt*16+m)
#pragma unroll
    for (int ks = 0; ks < 2; ks++) {
      bf16x8 xv = *(const bf16x8*)&x_dn[(wv * 16 + m) * 72 + ks * 32 + q * 8];
      bf16x8 p0 = *(const bf16x8*)&p_kn[(0 * 16 + m) * 72 + ks * 32 + q * 8];
      bf16x8 p1 = *(const bf16x8*)&p_kn[(1 * 16 + m) * 72 + ks * 32 + q * 8];
      bf16x8 p2 = *(const bf16x8*)&p_kn[(2 * 16 + m) * 72 + ks * 32 + q * 8];
      bf16x8 p3 = *(const bf16x8*)&p_kn[(3 * 16 + m) * 72 + ks * 32 + q * 8];
      accv0 = __builtin_amdgcn_mfma_f32_16x16x32_bf16(xv, p0, accv0, 0, 0, 0);
      accv1 = __builtin_amdgcn_mfma_f32_16x16x32_bf16(xv, p1, accv1, 0, 0, 0);
      accv2 = __builtin_amdgcn_mfma_f32_16x16x32_bf16(xv, p2, accv2, 0, 0, 0);
      accv3 = __builtin_amdgcn_mfma_f32_16x16x32_bf16(xv, p3, accv3, 0, 0, 0);
    }
    __syncthreads();   // bar_E: PV done before next stage overwrites LDS
  }

  // ---- epilogue: combine asum, centers correction, vlad write, colsq ----
  if (m == 0) {
#pragma unroll
    for (int r = 0; r < 4; r++)
      asum_sh[nsub][k16 * 16 + q * 4 + r] = asum_acc[r];
  }
  __syncthreads();

  f32x4 accs[4] = {accv0, accv1, accv2, accv3};
#pragma unroll
  for (int kt = 0; kt < 4; kt++) {
    int k = kt * 16 + m;
    float as = asum_sh[0][k] + asum_sh[1][k];
    float ss = 0.f;
#pragma unroll
    for (int r = 0; r < 4; r++) {
      int d = dbase + wv * 16 + q * 4 + r;
      float val = accs[kt][r] - centers[d * Kv + k] * as;
      vlad[((size_t)b * Dv + d) * Kv + k] = val;
      ss = fmaf(val, val, ss);
    }
    ss += __shfl_xor(ss, 16);
    ss += __shfl_xor(ss, 32);
    if (q == 0) atomicAdd(&colsq[b * Kv + k], ss);
  }
}

// ---------------------------------------------------------------------------
// Kernel D: out = vlad * colscale[b,k] * bscale[b]; scales from colsq
// in-block. Grid 4096 x 256.
// ---------------------------------------------------------------------------
__global__ __launch_bounds__(256) void scale_kernel(
    const float* __restrict__ vlad, const float* __restrict__ colsq,
    float* __restrict__ out) {
  const int t = threadIdx.x;
  const size_t i = (size_t)blockIdx.x * 256 + t;
  const int b = (int)(i >> 15);  // D*K = 32768 per b
  __shared__ float scs[64];
  __shared__ float bsh;
  if (t < 64) {
    float tot = colsq[b * Kv + t];
    float sc = 1.0f / fmaxf(sqrtf(tot), EPSv);
    scs[t] = sc;
    float contrib = tot * sc * sc;
#pragma unroll
    for (int off = 32; off > 0; off >>= 1) contrib += __shfl_down(contrib, off);
    if (t == 0) bsh = 1.0f / fmaxf(sqrtf(contrib), EPSv);
  }
  __syncthreads();
  out[i] = vlad[i] * scs[i & 63] * bsh;
}

extern "C" void kernel_launch(void* const* d_in, const int* in_sizes, int n_in,
                              void* d_out, int out_size, void* d_ws, size_t ws_size,
                              hipStream_t stream) {
  const float* x = (const float*)d_in[0];        // [B, D, N]
  const float* w = (const float*)d_in[1];        // [K, D]
  const float* centers = (const float*)d_in[2];  // [D, K]
  float* out = (float*)d_out;                    // [B, D*K]

  char* ws = (char*)d_ws;
  float* vlad = (float*)ws;                                   // [B][D][K] fp32, 4 MB
  unsigned short* wbf = (unsigned short*)(ws + 4194304);      // [K][D] bf16, 64 KB
  float* colsq = (float*)(ws + 4259840);                      // B*K fp32, 8 KB

  hipMemsetAsync(colsq, 0, (size_t)Bv * Kv * sizeof(float), stream);

  wconv<<<32, 256, 0, stream>>>(w, wbf);
  fused_all<<<128, 512, 0, stream>>>(x, wbf, centers, vlad, colsq);
  scale_kernel<<<(Bv * Dv * Kv) / 256, 256, 0, stream>>>(vlad, colsq, out);
}

// Round 6
// 143.526 us; speedup vs baseline: 1.2631x; 1.2631x over previous
//
#include <hip/hip_runtime.h>
#include <hip/hip_bf16.h>

#define Bv 32
#define Dv 512
#define Kv 64
#define Nv 1024
#define EPSv 1e-12f

typedef __attribute__((ext_vector_type(8))) short bf16x8;
typedef __attribute__((ext_vector_type(4))) float f32x4;

// fp32 -> bf16 (RNE), bit-level
__device__ __forceinline__ unsigned short f2b(float f) {
  union { float f; unsigned u; } v; v.f = f;
  unsigned r = v.u + 0x7fffu + ((v.u >> 16) & 1u);
  return (unsigned short)(r >> 16);
}
__device__ __forceinline__ unsigned pack2(float a, float b) {
  return (unsigned)f2b(a) | ((unsigned)f2b(b) << 16);
}

// ---------------------------------------------------------------------------
// Kernel W: convert conv_w (K x D fp32) -> bf16, AND zero asum+colsq
// (folds the former hipMemsetAsync dispatch away). 32 blocks x 256 thr.
// ---------------------------------------------------------------------------
__global__ __launch_bounds__(256) void wconv(const float* __restrict__ w,
                                             unsigned short* __restrict__ wbf,
                                             float* __restrict__ zbuf) {
  int id = blockIdx.x * 256 + threadIdx.x;
  int i = id * 4;
  float4 v = *(const float4*)&w[i];
  uint2 o = make_uint2(pack2(v.x, v.y), pack2(v.z, v.w));
  *(uint2*)&wbf[i] = o;
  if (id < 2 * Bv * Kv) zbuf[id] = 0.f;   // asum (B*K) + colsq (B*K) contiguous
}

// ---------------------------------------------------------------------------
// Kernel 1 (fused T+A) — unchanged from R9 (verified 145.26us config):
//  - tiled xbf writeback (vlad reads bf16 data freshly WRITTEN -> L2/L3-warm;
//    write-then-read is the empirically warm path, read-after-read is cold)
//  - tiled assign
//  - staging LDS rotation (bank-conflict fix) kept.
// Grid (N/64, B) = (16, 32) = 512 blocks, 512 threads (8 waves), 2 blk/CU.
// ---------------------------------------------------------------------------
__global__ __launch_bounds__(512) void fused_scores(
    const float* __restrict__ x, const unsigned short* __restrict__ wbf,
    unsigned short* __restrict__ xbf, unsigned short* __restrict__ assign,
    float* __restrict__ asum) {
  __shared__ unsigned short xT[64 * 520];   // [n][d], pitch 520 shorts (1040B)
  __shared__ float redmax[4][64];
  __shared__ float redsum[4][64];

  const int t = threadIdx.x;   // 0..511
  const int b = blockIdx.y;
  const int nt = blockIdx.x;
  const int n0 = nt * 64;

  // ---------------- staging (+ tiled xbf writeback) ----------------
  {
    const int lo = t & 15;     // n-quad
    const int hi = t >> 4;     // 0..31 (d-pair subindex)
    const int s = (lo >> 1) & 3;   // write-rotation amount (bank spread)
    const float* xb = x + (size_t)b * Dv * Nv + n0;
    unsigned short* xt = xbf + ((size_t)b * 16 + nt) * (Dv * 64);
#pragma unroll
    for (int r = 0; r < 8; r++) {
      int d = (hi + 32 * r) * 2;        // even d row; covers 0..510
      int n4 = lo * 4;
      float4 v0 = *(const float4*)&xb[(size_t)d * Nv + n4];
      float4 v1 = *(const float4*)&xb[(size_t)(d + 1) * Nv + n4];
      // tiled xbf write: row-major within 64KB tile, dense windows
      *(uint2*)&xt[(size_t)d * 64 + n4] =
          make_uint2(pack2(v0.x, v0.y), pack2(v0.z, v0.w));
      *(uint2*)&xt[(size_t)(d + 1) * 64 + n4] =
          make_uint2(pack2(v1.x, v1.y), pack2(v1.z, v1.w));
      // LDS xT: dword at [n][d] = (x[d][n], x[d+1][n]); d even -> aligned
      unsigned w0 = pack2(v0.x, v1.x);
      unsigned w1 = pack2(v0.y, v1.y);
      unsigned w2 = pack2(v0.z, v1.z);
      unsigned w3 = pack2(v0.w, v1.w);
      // rotate data+row-offset by s: instruction j writes row n4+((j+s)&3)
      unsigned a0 = (s & 1) ? w1 : w0, a1 = (s & 1) ? w2 : w1,
               a2 = (s & 1) ? w3 : w2, a3 = (s & 1) ? w0 : w3;
      unsigned b0 = (s & 2) ? a2 : a0, b1 = (s & 2) ? a3 : a1,
               b2 = (s & 2) ? a0 : a2, b3 = (s & 2) ? a1 : a3;
      *(unsigned*)&xT[(n4 + ((0 + s) & 3)) * 520 + d] = b0;
      *(unsigned*)&xT[(n4 + ((1 + s) & 3)) * 520 + d] = b1;
      *(unsigned*)&xT[(n4 + ((2 + s) & 3)) * 520 + d] = b2;
      *(unsigned*)&xT[(n4 + ((3 + s) & 3)) * 520 + d] = b3;
    }
  }
  __syncthreads();

  // ---------------- scores GEMM ----------------
  const int wv = t >> 6;        // 0..7
  const int lane = t & 63;
  const int q = lane >> 4;
  const int m = lane & 15;
  const int k16 = wv & 3;       // k-tile
  const int nsub = wv >> 2;     // n-half: cols [nsub*32, +32)

  f32x4 acc0 = {0.f, 0.f, 0.f, 0.f};
  f32x4 acc1 = {0.f, 0.f, 0.f, 0.f};

  const unsigned short* wp = wbf + (size_t)(k16 * 16 + m) * Dv + q * 8;
  const unsigned short* l0 = &xT[(nsub * 32 + m) * 520 + q * 8];
  const unsigned short* l1 = l0 + 16 * 520;

#pragma unroll
  for (int d0 = 0; d0 < Dv; d0 += 32) {
    bf16x8 af = *(const bf16x8*)(wp + d0);
    bf16x8 bf0 = *(const bf16x8*)(l0 + d0);
    bf16x8 bf1 = *(const bf16x8*)(l1 + d0);
    acc0 = __builtin_amdgcn_mfma_f32_16x16x32_bf16(af, bf0, acc0, 0, 0, 0);
    acc1 = __builtin_amdgcn_mfma_f32_16x16x32_bf16(af, bf1, acc1, 0, 0, 0);
  }

  // ---------------- softmax over k (64) ----------------
  float m0 = fmaxf(fmaxf(acc0[0], acc0[1]), fmaxf(acc0[2], acc0[3]));
  float m1 = fmaxf(fmaxf(acc1[0], acc1[1]), fmaxf(acc1[2], acc1[3]));
  m0 = fmaxf(m0, __shfl_xor(m0, 16)); m0 = fmaxf(m0, __shfl_xor(m0, 32));
  m1 = fmaxf(m1, __shfl_xor(m1, 16)); m1 = fmaxf(m1, __shfl_xor(m1, 32));
  if (q == 0) {
    redmax[k16][nsub * 32 + m] = m0;
    redmax[k16][nsub * 32 + 16 + m] = m1;
  }
  __syncthreads();
  const int c0 = nsub * 32 + m, c1 = c0 + 16;
  float mc0 = fmaxf(fmaxf(redmax[0][c0], redmax[1][c0]), fmaxf(redmax[2][c0], redmax[3][c0]));
  float mc1 = fmaxf(fmaxf(redmax[0][c1], redmax[1][c1]), fmaxf(redmax[2][c1], redmax[3][c1]));

  float e0[4], e1[4];
  float s0 = 0.f, s1 = 0.f;
#pragma unroll
  for (int r = 0; r < 4; r++) {
    e0[r] = __expf(acc0[r] - mc0); s0 += e0[r];
    e1[r] = __expf(acc1[r] - mc1); s1 += e1[r];
  }
  s0 += __shfl_xor(s0, 16); s0 += __shfl_xor(s0, 32);
  s1 += __shfl_xor(s1, 16); s1 += __shfl_xor(s1, 32);
  if (q == 0) {
    redsum[k16][c0] = s0;
    redsum[k16][c1] = s1;
  }
  __syncthreads();
  float sc0 = 1.0f / (redsum[0][c0] + redsum[1][c0] + redsum[2][c0] + redsum[3][c0]);
  float sc1 = 1.0f / (redsum[0][c1] + redsum[1][c1] + redsum[2][c1] + redsum[3][c1]);

  // ---------------- assign write (tiled) + asum ----------------
  unsigned short* at_ = assign + ((size_t)b * 16 + nt) * (Kv * 64)
                        + (size_t)(k16 * 16 + q * 4) * 64 + nsub * 32;
#pragma unroll
  for (int r = 0; r < 4; r++) {
    float v0 = e0[r] * sc0;
    float v1 = e1[r] * sc1;
    at_[r * 64 + m] = f2b(v0);
    at_[r * 64 + 16 + m] = f2b(v1);
    float p = v0 + v1;
    p += __shfl_xor(p, 1); p += __shfl_xor(p, 2);
    p += __shfl_xor(p, 4); p += __shfl_xor(p, 8);
    if (m == 0) atomicAdd(&asum[b * Kv + k16 * 16 + q * 4 + r], p);
  }
}

// ---------------------------------------------------------------------------
// Kernel 2 — body unchanged from R9; grid now 1D-1024 with a bijective
// XCD swizzle so all 32 d-blocks of one b land on the SAME XCD:
//   xcd = flat&7, loc = flat>>3; b = (loc>>5)*8 + xcd; dblk = loc&31.
// -> assign[b] (128 KB) is L2-reused 32x; xbf[b] (1 MB) fetched once/XCD.
// ---------------------------------------------------------------------------
__global__ __launch_bounds__(512, 2) void vlad_mfma(
    const unsigned short* __restrict__ xbf, const unsigned short* __restrict__ assign,
    const float* __restrict__ centers, const float* __restrict__ asum,
    float* __restrict__ vlad, float* __restrict__ colsq) {
  __shared__ float sred[4][64][4];   // [ksub][lane][r] from nh==1 waves

  const int t = threadIdx.x;
  const int flat = blockIdx.x;       // 0..1023
  const int loc = flat >> 3;         // 0..127
  const int b = ((loc >> 5) << 3) + (flat & 7);   // 0..31, co-XCD per b
  const int d0 = (loc & 31) * 16;
  const int wv = t >> 6;
  const int ksub = wv & 3;
  const int nh = wv >> 2;            // n-half: tiles nh*8 .. nh*8+7
  const int lane = t & 63;
  const int q = lane >> 4;
  const int m = lane & 15;
  const int k16 = ksub * 16;

  // group g (0..15): tile = g>>1, chunk = g&1
  const unsigned short* xp = xbf + ((size_t)b * 16 + nh * 8) * (Dv * 64)
                             + (size_t)(d0 + m) * 64 + q * 8;
  const unsigned short* ap = assign + ((size_t)b * 16 + nh * 8) * (Kv * 64)
                             + (size_t)(k16 + m) * 64 + q * 8;

  f32x4 acc = {0.f, 0.f, 0.f, 0.f};
  bf16x8 xv[8], av[8];

  // prologue: 16 loads in flight (groups 0..7)
#pragma unroll
  for (int i = 0; i < 8; i++) {
    xv[i] = *(const bf16x8*)(xp + (i >> 1) * (Dv * 64) + (i & 1) * 32);
    av[i] = *(const bf16x8*)(ap + (i >> 1) * (Kv * 64) + (i & 1) * 32);
  }
  __builtin_amdgcn_sched_barrier(0);

  // steady: consume group i, refill slot with group i+8
#pragma unroll
  for (int i = 0; i < 8; i++) {
    acc = __builtin_amdgcn_mfma_f32_16x16x32_bf16(xv[i], av[i], acc, 0, 0, 0);
    xv[i] = *(const bf16x8*)(xp + ((i + 8) >> 1) * (Dv * 64) + (i & 1) * 32);
    av[i] = *(const bf16x8*)(ap + ((i + 8) >> 1) * (Kv * 64) + (i & 1) * 32);
    __builtin_amdgcn_sched_barrier(0);
  }

  // drain
#pragma unroll
  for (int i = 0; i < 8; i++)
    acc = __builtin_amdgcn_mfma_f32_16x16x32_bf16(xv[i], av[i], acc, 0, 0, 0);

  if (nh == 1) {
#pragma unroll
    for (int r = 0; r < 4; r++) sred[ksub][lane][r] = acc[r];
  }
  __syncthreads();
  if (nh == 0) {
    const int k = k16 + m;
    const float as = asum[b * Kv + k];
    float ss = 0.f;
#pragma unroll
    for (int r = 0; r < 4; r++) {
      float v = acc[r] + sred[ksub][lane][r];
      int d = d0 + q * 4 + r;
      float val = v - centers[d * Kv + k] * as;
      vlad[((size_t)b * Dv + d) * Kv + k] = val;
      ss = fmaf(val, val, ss);
    }
    ss += __shfl_xor(ss, 16);
    ss += __shfl_xor(ss, 32);
    if (q == 0) atomicAdd(&colsq[b * Kv + k], ss);
  }
}

// ---------------------------------------------------------------------------
// Kernel D: out = vlad * colscale[b,k] * bscale[b]; float4-vectorized
// (16 B/lane). Grid 1024 x 256.
// ---------------------------------------------------------------------------
__global__ __launch_bounds__(256) void scale_kernel(
    const float* __restrict__ vlad, const float* __restrict__ colsq,
    float* __restrict__ out) {
  const int t = threadIdx.x;
  const size_t i = ((size_t)blockIdx.x * 256 + t) * 4;
  const int b = (int)(i >> 15);  // D*K = 32768 per b
  __shared__ float scs[64];
  __shared__ float bsh;
  if (t < 64) {
    float tot = colsq[b * Kv + t];
    float sc = 1.0f / fmaxf(sqrtf(tot), EPSv);
    scs[t] = sc;
    float contrib = tot * sc * sc;
#pragma unroll
    for (int off = 32; off > 0; off >>= 1) contrib += __shfl_down(contrib, off);
    if (t == 0) bsh = 1.0f / fmaxf(sqrtf(contrib), EPSv);
  }
  __syncthreads();
  float4 v = *(const float4*)&vlad[i];
  const int k = (int)(i & 63);          // 4-aligned, same b for all 4
  float4 o;
  o.x = v.x * scs[k + 0] * bsh;
  o.y = v.y * scs[k + 1] * bsh;
  o.z = v.z * scs[k + 2] * bsh;
  o.w = v.w * scs[k + 3] * bsh;
  *(float4*)&out[i] = o;
}

extern "C" void kernel_launch(void* const* d_in, const int* in_sizes, int n_in,
                              void* d_out, int out_size, void* d_ws, size_t ws_size,
                              hipStream_t stream) {
  const float* x = (const float*)d_in[0];        // [B, D, N]
  const float* w = (const float*)d_in[1];        // [K, D]
  const float* centers = (const float*)d_in[2];  // [D, K]
  float* out = (float*)d_out;                    // [B, D*K]

  char* ws = (char*)d_ws;
  unsigned short* assign = (unsigned short*)ws;               // tiled, 4 MB
  float* vlad = (float*)(ws + 4194304);                       // [B][D][K] fp32, 4 MB
  unsigned short* xbf = (unsigned short*)(ws + 8388608);      // tiled bf16, 32 MB
  unsigned short* wbf = (unsigned short*)(ws + 41943040);     // [K][D] bf16, 64 KB
  float* asum = (float*)(ws + 42008576);                      // B*K
  float* colsq = asum + Bv * Kv;                              // B*K (contiguous)

  wconv<<<32, 256, 0, stream>>>(w, wbf, asum);   // also zeros asum+colsq
  fused_scores<<<dim3(Nv / 64, Bv), 512, 0, stream>>>(x, wbf, xbf, assign, asum);
  vlad_mfma<<<1024, 512, 0, stream>>>(xbf, assign, centers, asum, vlad, colsq);
  scale_kernel<<<1024, 256, 0, stream>>>(vlad, colsq, out);
}